// Round 5
// baseline (336.104 us; speedup 1.0000x reference)
//
#include <hip/hip_runtime.h>

#define NN 100000
#define DD 128
#define EE 640000
#define NPAD 100352  // NN rounded up to 256 multiple

typedef __bf16 bf16x8 __attribute__((ext_vector_type(8)));
typedef float floatx4 __attribute__((ext_vector_type(4)));

union BF8 {
    bf16x8 v;
    unsigned short u[8];
    int4 i4;
};

__device__ __forceinline__ unsigned short f2bf(float f) {
    unsigned int u = __float_as_uint(f);
    u += 0x7FFF + ((u >> 16) & 1);   // round-to-nearest-even
    return (unsigned short)(u >> 16);
}

// ---------------------------------------------------------------------------
// CSR build: histogram -> 3-kernel exclusive scan -> bucket scatter
// ---------------------------------------------------------------------------
__global__ __launch_bounds__(256) void hist_k(const int* __restrict__ ei,
                                              int* __restrict__ deg) {
    int e = blockIdx.x * 256 + threadIdx.x;
    if (e < EE) atomicAdd(&deg[ei[EE + e]], 1);
}

__global__ __launch_bounds__(256) void scan1_k(const int* __restrict__ deg,
                                               int* __restrict__ exc,
                                               int* __restrict__ chunkSums) {
    __shared__ int s[256];
    int t = threadIdx.x, g = blockIdx.x * 256 + t;
    int v = (g < NN) ? deg[g] : 0;
    s[t] = v;
    __syncthreads();
    for (int off = 1; off < 256; off <<= 1) {
        int u = (t >= off) ? s[t - off] : 0;
        __syncthreads();
        s[t] += u;
        __syncthreads();
    }
    if (g < NN) exc[g] = s[t] - v;
    if (t == 255) chunkSums[blockIdx.x] = s[255];
}

__global__ __launch_bounds__(512) void scan2_k(int* __restrict__ chunkSums, int n) {
    __shared__ int s[512];
    int t = threadIdx.x;
    int v = (t < n) ? chunkSums[t] : 0;
    s[t] = v;
    __syncthreads();
    for (int off = 1; off < 512; off <<= 1) {
        int u = (t >= off) ? s[t - off] : 0;
        __syncthreads();
        s[t] += u;
        __syncthreads();
    }
    if (t < n) chunkSums[t] = s[t] - v;  // exclusive
}

__global__ __launch_bounds__(256) void scan3_k(int* __restrict__ exc,
                                               const int* __restrict__ chunkSums,
                                               int* __restrict__ cursor) {
    int g = blockIdx.x * 256 + threadIdx.x;
    if (g < NN) {
        int o = exc[g] + chunkSums[blockIdx.x];
        exc[g] = o;
        cursor[g] = o;
    }
}

__global__ __launch_bounds__(256) void esort_k(const int* __restrict__ ei,
                                               int* __restrict__ cursor,
                                               int* __restrict__ ssrc) {
    int e = blockIdx.x * 256 + threadIdx.x;
    if (e >= EE) return;
    int pos = atomicAdd(&cursor[ei[EE + e]], 1);
    ssrc[pos] = ei[e];
}

// ---------------------------------------------------------------------------
// W fp32 -> bf16 preconvert (both layers, once). 32 blocks, ~2 us.
// ---------------------------------------------------------------------------
__global__ __launch_bounds__(256) void wconv_k(const float* __restrict__ W1,
                                               const float* __restrict__ W2,
                                               unsigned short* __restrict__ wb) {
    int i = blockIdx.x * 256 + threadIdx.x;  // float4 units, 0..8191
    const float4* s4 = (i < 4096) ? (const float4*)W1 : (const float4*)W2;
    float4 v = s4[i & 4095];
    ushort4 u;
    u.x = f2bf(v.x); u.y = f2bf(v.y); u.z = f2bf(v.z); u.w = f2bf(v.w);
    ((ushort4*)wb)[i] = u;
}

// ---------------------------------------------------------------------------
// aggregate + fuse: h[node] = bf16((1+eps)*x[node] + sum_{src in CSR} x[src])
// 32 lanes (float4) per node. Round-4 lesson: without launch_bounds the
// compiler capped at 20 VGPR and SERIALIZED the "4-wide" gathers. Now:
// launch_bounds(256,4) (<=64 VGPR) + 8-wide predicated unroll -> 8 row
// gathers genuinely in flight. Edge-order summation preserved (bitwise
// identical result).
// ---------------------------------------------------------------------------
__global__ __launch_bounds__(256, 4) void aggregate_k(
    const float4* __restrict__ x4, const int* __restrict__ ssrc,
    const int* __restrict__ offs, const int* __restrict__ deg,
    const float* __restrict__ epsp, ushort4* __restrict__ hout) {
    int tid = blockIdx.x * 256 + threadIdx.x;
    int node = tid >> 5, lane = tid & 31;
    if (node >= NN) return;
    int start = offs[node], d = deg[node];
    float ef = 1.0f + epsp[0];
    float4 v = x4[node * 32 + lane];
    float ax = ef * v.x, ay = ef * v.y, az = ef * v.z, aw = ef * v.w;
    for (int j = 0; j < d; j += 8) {
        int r = d - j;          // >= 1
        int b = start + j;
        int s0 = ssrc[b];
        int s1 = ssrc[b + ((r > 1) ? 1 : 0)];
        int s2 = ssrc[b + ((r > 2) ? 2 : 0)];
        int s3 = ssrc[b + ((r > 3) ? 3 : 0)];
        int s4i = ssrc[b + ((r > 4) ? 4 : 0)];
        int s5 = ssrc[b + ((r > 5) ? 5 : 0)];
        int s6 = ssrc[b + ((r > 6) ? 6 : 0)];
        int s7 = ssrc[b + ((r > 7) ? 7 : 0)];
        float4 x0 = x4[s0 * 32 + lane];
        float4 x1 = x4[s1 * 32 + lane];
        float4 x2 = x4[s2 * 32 + lane];
        float4 x3 = x4[s3 * 32 + lane];
        float4 x4v = x4[s4i * 32 + lane];
        float4 x5 = x4[s5 * 32 + lane];
        float4 x6 = x4[s6 * 32 + lane];
        float4 x7 = x4[s7 * 32 + lane];
        float m1 = (r > 1) ? 1.f : 0.f;
        float m2 = (r > 2) ? 1.f : 0.f;
        float m3 = (r > 3) ? 1.f : 0.f;
        float m4 = (r > 4) ? 1.f : 0.f;
        float m5 = (r > 5) ? 1.f : 0.f;
        float m6 = (r > 6) ? 1.f : 0.f;
        float m7 = (r > 7) ? 1.f : 0.f;
        ax += x0.x; ay += x0.y; az += x0.z; aw += x0.w;
        ax += m1 * x1.x; ay += m1 * x1.y; az += m1 * x1.z; aw += m1 * x1.w;
        ax += m2 * x2.x; ay += m2 * x2.y; az += m2 * x2.z; aw += m2 * x2.w;
        ax += m3 * x3.x; ay += m3 * x3.y; az += m3 * x3.z; aw += m3 * x3.w;
        ax += m4 * x4v.x; ay += m4 * x4v.y; az += m4 * x4v.z; aw += m4 * x4v.w;
        ax += m5 * x5.x; ay += m5 * x5.y; az += m5 * x5.z; aw += m5 * x5.w;
        ax += m6 * x6.x; ay += m6 * x6.y; az += m6 * x6.z; aw += m6 * x6.w;
        ax += m7 * x7.x; ay += m7 * x7.y; az += m7 * x7.z; aw += m7 * x7.w;
    }
    ushort4 u;
    u.x = f2bf(ax); u.y = f2bf(ay); u.z = f2bf(az); u.w = f2bf(aw);
    hout[node * 32 + lane] = u;
}

// ---------------------------------------------------------------------------
// Persistent-W GEMM + bias + BN-stat accumulation.
// Each wave holds the ENTIRE bf16 W in registers (32 x bf16x8 = 128 VGPR)
// and grid-strides over 16-row A-tiles (prefetch 1 tile ahead; tiles of a
// residue class belong to one wave -> in-place y allowed).
// FUSE_BN=0: A = bf16 hin.
// FUSE_BN=1: A = fp32 yin; BN(statsIn,gmm,bta)+ReLU applied in the loader
//            (sc/sh from LDS; bitwise-identical rounding to the old
//            standalone bn_relu<1> pass). Enables in-place y1->y2.
// ---------------------------------------------------------------------------
template <int FUSE_BN>
__global__ __launch_bounds__(256, 2) void gin_gemm_k(
    const unsigned short* __restrict__ hin,
    const float* __restrict__ yin,
    const float* __restrict__ statsIn,
    const float* __restrict__ gmm,
    const float* __restrict__ bta,
    const unsigned short* __restrict__ Wbf, const float* __restrict__ bias,
    float* __restrict__ y, float* __restrict__ statsOut) {
    __shared__ __align__(16) float s_sum[128];
    __shared__ __align__(16) float s_sq[128];
    __shared__ __align__(16) float sc[128];
    __shared__ __align__(16) float sh[128];

    const int tid = threadIdx.x;
    const int l = tid & 63, w = tid >> 6;
    const int m = l & 15, q = l >> 4;

    if (tid < 128) {
        s_sum[tid] = 0.f;
        s_sq[tid] = 0.f;
        if (FUSE_BN) {
            const float inv = 1.0f / (float)NN;
            float mean = statsIn[tid] * inv;
            float var = statsIn[128 + tid] * inv - mean * mean;
            float s = gmm[tid] * rsqrtf(var + 1e-5f);
            sc[tid] = s;
            sh[tid] = bta[tid] - mean * s;
        }
    }

    // --- whole W into registers, once per wave ---
    bf16x8 wf[8][4];
#pragma unroll
    for (int ct = 0; ct < 8; ++ct) {
        const unsigned short* wr = Wbf + (size_t)(ct * 16 + m) * 128 + q * 8;
#pragma unroll
        for (int kc = 0; kc < 4; ++kc) {
            BF8 t;
            t.i4 = *(const int4*)(wr + kc * 32);
            wf[ct][kc] = t.v;
        }
    }
    float bc[8];
#pragma unroll
    for (int ct = 0; ct < 8; ++ct) bc[ct] = bias[ct * 16 + m];

    float ps[8], pq[8];
#pragma unroll
    for (int ct = 0; ct < 8; ++ct) { ps[ct] = 0.f; pq[ct] = 0.f; }

    __syncthreads();  // s_sum/s_sq (and sc/sh) visible

    const int NT = NN / 16;              // 6250, exact
    const int stride = gridDim.x * 4;    // waves total
    int t = blockIdx.x * 4 + w;

    const unsigned short* abase = hin + (size_t)m * 128 + q * 8;
    const float* ybase = yin + (size_t)m * 128 + q * 8;

    int4 ra[4];      // FUSE_BN=0 prefetch
    float4 rf[8];    // FUSE_BN=1 prefetch
    if (t < NT) {
        if (FUSE_BN) {
            const float* yp = ybase + (size_t)t * (16 * 128);
#pragma unroll
            for (int i = 0; i < 8; ++i)
                rf[i] = *(const float4*)(yp + (i >> 1) * 32 + (i & 1) * 4);
        } else {
            const unsigned short* ap = abase + (size_t)t * (16 * 128);
#pragma unroll
            for (int kc = 0; kc < 4; ++kc) ra[kc] = *(const int4*)(ap + kc * 32);
        }
    }

    while (t < NT) {
        // consume prefetched raw A into bf16 fragment regs
        bf16x8 a[4];
#pragma unroll
        for (int kc = 0; kc < 4; ++kc) {
            if (FUSE_BN) {
                float4 v0 = rf[2 * kc], v1 = rf[2 * kc + 1];
                float4 s0 = *(const float4*)(sc + kc * 32 + q * 8);
                float4 s1 = *(const float4*)(sc + kc * 32 + q * 8 + 4);
                float4 h0 = *(const float4*)(sh + kc * 32 + q * 8);
                float4 h1 = *(const float4*)(sh + kc * 32 + q * 8 + 4);
                BF8 tt;
                tt.u[0] = f2bf(fmaxf(v0.x * s0.x + h0.x, 0.f));
                tt.u[1] = f2bf(fmaxf(v0.y * s0.y + h0.y, 0.f));
                tt.u[2] = f2bf(fmaxf(v0.z * s0.z + h0.z, 0.f));
                tt.u[3] = f2bf(fmaxf(v0.w * s0.w + h0.w, 0.f));
                tt.u[4] = f2bf(fmaxf(v1.x * s1.x + h1.x, 0.f));
                tt.u[5] = f2bf(fmaxf(v1.y * s1.y + h1.y, 0.f));
                tt.u[6] = f2bf(fmaxf(v1.z * s1.z + h1.z, 0.f));
                tt.u[7] = f2bf(fmaxf(v1.w * s1.w + h1.w, 0.f));
                a[kc] = tt.v;
            } else {
                BF8 tt;
                tt.i4 = ra[kc];
                a[kc] = tt.v;
            }
        }

        // issue next tile's loads before compute (hidden under MFMA+stores)
        int tn = t + stride;
        if (tn < NT) {
            if (FUSE_BN) {
                const float* yp = ybase + (size_t)tn * (16 * 128);
#pragma unroll
                for (int i = 0; i < 8; ++i)
                    rf[i] = *(const float4*)(yp + (i >> 1) * 32 + (i & 1) * 4);
            } else {
                const unsigned short* ap = abase + (size_t)tn * (16 * 128);
#pragma unroll
                for (int kc = 0; kc < 4; ++kc) ra[kc] = *(const int4*)(ap + kc * 32);
            }
        }

        floatx4 acc[8];
#pragma unroll
        for (int ct = 0; ct < 8; ++ct) acc[ct] = (floatx4)0.0f;
#pragma unroll
        for (int kc = 0; kc < 4; ++kc)
#pragma unroll
            for (int ct = 0; ct < 8; ++ct)
                acc[ct] = __builtin_amdgcn_mfma_f32_16x16x32_bf16(a[kc], wf[ct][kc], acc[ct], 0, 0, 0);

        // epilogue: bias, store y (row = t*16 + q*4 + i, col = ct*16 + m)
        float* yb = y + (size_t)(t * 16 + q * 4) * 128 + m;
#pragma unroll
        for (int ct = 0; ct < 8; ++ct) {
#pragma unroll
            for (int i = 0; i < 4; ++i) {
                float yv = acc[ct][i] + bc[ct];
                yb[(size_t)i * 128 + ct * 16] = yv;
                ps[ct] += yv;
                pq[ct] += yv * yv;
            }
        }
        t = tn;
    }

    // flush register stats: LDS reduce, then 2 global atomics per column
#pragma unroll
    for (int ct = 0; ct < 8; ++ct) {
        atomicAdd(&s_sum[ct * 16 + m], ps[ct]);
        atomicAdd(&s_sq[ct * 16 + m], pq[ct]);
    }
    __syncthreads();
    if (tid < 128) {
        unsafeAtomicAdd(&statsOut[tid], s_sum[tid]);
        unsafeAtomicAdd(&statsOut[128 + tid], s_sq[tid]);
    }
}

// ---------------------------------------------------------------------------
// BN(train, biased var) + ReLU, fp32 in place (final layer only).
// ---------------------------------------------------------------------------
__global__ __launch_bounds__(256) void bn_relu_k(
    const float* __restrict__ y, const float* __restrict__ stats,
    const float* __restrict__ g, const float* __restrict__ beta,
    float* __restrict__ outf) {
    __shared__ __align__(16) float sc[128];
    __shared__ __align__(16) float sh[128];
    int t = threadIdx.x;
    if (t < 128) {
        const float inv = 1.0f / (float)NN;
        float mean = stats[t] * inv;
        float var = stats[128 + t] * inv - mean * mean;
        float s = g[t] * rsqrtf(var + 1e-5f);
        sc[t] = s;
        sh[t] = beta[t] - mean * s;
    }
    __syncthreads();
    const int total4 = NN * 32;
    const float4* y4 = (const float4*)y;
    for (int i = blockIdx.x * 256 + t; i < total4; i += gridDim.x * 256) {
        int c4 = i & 31;
        float4 v = y4[i];
        float4 s = ((const float4*)sc)[c4];
        float4 b = ((const float4*)sh)[c4];
        float r0 = fmaxf(v.x * s.x + b.x, 0.f);
        float r1 = fmaxf(v.y * s.y + b.y, 0.f);
        float r2 = fmaxf(v.z * s.z + b.z, 0.f);
        float r3 = fmaxf(v.w * s.w + b.w, 0.f);
        ((float4*)outf)[i] = make_float4(r0, r1, r2, r3);
    }
}

// ---------------------------------------------------------------------------
extern "C" void kernel_launch(void* const* d_in, const int* in_sizes, int n_in,
                              void* d_out, int out_size, void* d_ws, size_t ws_size,
                              hipStream_t stream) {
    const float* x   = (const float*)d_in[0];
    const int* ei    = (const int*)d_in[1];   // int64 in ref -> int32 from harness
    const float* eps = (const float*)d_in[2];
    const float* W1  = (const float*)d_in[3];
    const float* b1  = (const float*)d_in[4];
    const float* g1  = (const float*)d_in[5];
    const float* be1 = (const float*)d_in[6];
    const float* W2  = (const float*)d_in[7];
    const float* b2  = (const float*)d_in[8];
    const float* g2  = (const float*)d_in[9];
    const float* be2 = (const float*)d_in[10];
    float* out = (float*)d_out;

    // Workspace (~29.6 MB): [csr][hbuf bf16 25.6MB][stats 2KB][wbf 64KB]
    // gemm1 hbuf->out (y1); gemm2 reads y1 with fused BN1+ReLU, in-place ->
    // out (y2); bn_relu finishes BN2 in place.
    int* deg        = (int*)d_ws;           // NPAD
    int* offs       = deg + NPAD;           // NPAD
    int* cursor     = offs + NPAD;          // NPAD
    int* chunkSums  = cursor + NPAD;        // 512
    int* ssrc       = chunkSums + 512;      // EE + pad
    unsigned short* hbuf = (unsigned short*)(ssrc + EE + 256);   // N*D bf16
    float* stats    = (float*)(hbuf + (size_t)NN * DD);          // 512
    unsigned short* wbf = (unsigned short*)(stats + 512);        // 2*128*128 bf16

    hipMemsetAsync(deg, 0, NPAD * sizeof(int), stream);
    hipMemsetAsync(stats, 0, 512 * sizeof(float), stream);

    const int numChunks = (NN + 255) / 256;  // 391
    hist_k<<<(EE + 255) / 256, 256, 0, stream>>>(ei, deg);
    scan1_k<<<numChunks, 256, 0, stream>>>(deg, offs, chunkSums);
    scan2_k<<<1, 512, 0, stream>>>(chunkSums, numChunks);
    scan3_k<<<numChunks, 256, 0, stream>>>(offs, chunkSums, cursor);
    esort_k<<<(EE + 255) / 256, 256, 0, stream>>>(ei, cursor, ssrc);
    aggregate_k<<<(NN * 32 + 255) / 256, 256, 0, stream>>>(
        (const float4*)x, ssrc, offs, deg, eps, (ushort4*)hbuf);
    wconv_k<<<32, 256, 0, stream>>>(W1, W2, wbf);

    const int gblocks = 512;  // ~2 blocks/CU, persistent grid-stride
    gin_gemm_k<0><<<gblocks, 256, 0, stream>>>(
        hbuf, nullptr, nullptr, nullptr, nullptr, wbf, b1, out, stats);
    gin_gemm_k<1><<<gblocks, 256, 0, stream>>>(
        nullptr, out, stats, g1, be1, wbf + 16384, b2, out, stats + 256);
    bn_relu_k<<<4096, 256, 0, stream>>>(out, stats + 256, g2, be2, out);
}

// Round 6
// 322.774 us; speedup vs baseline: 1.0413x; 1.0413x over previous
//
#include <hip/hip_runtime.h>

#define NN 100000
#define DD 128
#define EE 640000
#define NPAD 100352  // NN rounded up to 256 multiple

typedef __bf16 bf16x8 __attribute__((ext_vector_type(8)));
typedef float floatx4 __attribute__((ext_vector_type(4)));

union BF8 {
    bf16x8 v;
    unsigned short u[8];
    int4 i4;
};

__device__ __forceinline__ unsigned short f2bf(float f) {
    unsigned int u = __float_as_uint(f);
    u += 0x7FFF + ((u >> 16) & 1);   // round-to-nearest-even
    return (unsigned short)(u >> 16);
}

// ---------------------------------------------------------------------------
// CSR build: histogram -> 3-kernel exclusive scan -> bucket scatter
// ---------------------------------------------------------------------------
__global__ __launch_bounds__(256) void hist_k(const int* __restrict__ ei,
                                              int* __restrict__ deg) {
    int e = blockIdx.x * 256 + threadIdx.x;
    if (e < EE) atomicAdd(&deg[ei[EE + e]], 1);
}

__global__ __launch_bounds__(256) void scan1_k(const int* __restrict__ deg,
                                               int* __restrict__ exc,
                                               int* __restrict__ chunkSums) {
    __shared__ int s[256];
    int t = threadIdx.x, g = blockIdx.x * 256 + t;
    int v = (g < NN) ? deg[g] : 0;
    s[t] = v;
    __syncthreads();
    for (int off = 1; off < 256; off <<= 1) {
        int u = (t >= off) ? s[t - off] : 0;
        __syncthreads();
        s[t] += u;
        __syncthreads();
    }
    if (g < NN) exc[g] = s[t] - v;
    if (t == 255) chunkSums[blockIdx.x] = s[255];
}

__global__ __launch_bounds__(512) void scan2_k(int* __restrict__ chunkSums, int n) {
    __shared__ int s[512];
    int t = threadIdx.x;
    int v = (t < n) ? chunkSums[t] : 0;
    s[t] = v;
    __syncthreads();
    for (int off = 1; off < 512; off <<= 1) {
        int u = (t >= off) ? s[t - off] : 0;
        __syncthreads();
        s[t] += u;
        __syncthreads();
    }
    if (t < n) chunkSums[t] = s[t] - v;  // exclusive
}

__global__ __launch_bounds__(256) void scan3_k(int* __restrict__ exc,
                                               const int* __restrict__ chunkSums,
                                               int* __restrict__ cursor) {
    int g = blockIdx.x * 256 + threadIdx.x;
    if (g < NN) {
        int o = exc[g] + chunkSums[blockIdx.x];
        exc[g] = o;
        cursor[g] = o;
    }
}

__global__ __launch_bounds__(256) void esort_k(const int* __restrict__ ei,
                                               int* __restrict__ cursor,
                                               int* __restrict__ ssrc) {
    int e = blockIdx.x * 256 + threadIdx.x;
    if (e >= EE) return;
    int pos = atomicAdd(&cursor[ei[EE + e]], 1);
    ssrc[pos] = ei[e];
}

// ---------------------------------------------------------------------------
// W fp32 -> bf16 preconvert (both layers, once). 32 blocks, ~2 us.
// ---------------------------------------------------------------------------
__global__ __launch_bounds__(256) void wconv_k(const float* __restrict__ W1,
                                               const float* __restrict__ W2,
                                               unsigned short* __restrict__ wb) {
    int i = blockIdx.x * 256 + threadIdx.x;  // float4 units, 0..8191
    const float4* s4 = (i < 4096) ? (const float4*)W1 : (const float4*)W2;
    float4 v = s4[i & 4095];
    ushort4 u;
    u.x = f2bf(v.x); u.y = f2bf(v.y); u.z = f2bf(v.z); u.w = f2bf(v.w);
    ((ushort4*)wb)[i] = u;
}

// ---------------------------------------------------------------------------
// aggregate + fuse: h[node] = bf16((1+eps)*x[node] + sum_{src in CSR} x[src])
// 32 lanes (float4) per node; launch_bounds(256,4) + 8-wide predicated
// unroll -> 8 row gathers in flight (round-4 lesson: 20-VGPR cap serialized).
// ---------------------------------------------------------------------------
__global__ __launch_bounds__(256, 4) void aggregate_k(
    const float4* __restrict__ x4, const int* __restrict__ ssrc,
    const int* __restrict__ offs, const int* __restrict__ deg,
    const float* __restrict__ epsp, ushort4* __restrict__ hout) {
    int tid = blockIdx.x * 256 + threadIdx.x;
    int node = tid >> 5, lane = tid & 31;
    if (node >= NN) return;
    int start = offs[node], d = deg[node];
    float ef = 1.0f + epsp[0];
    float4 v = x4[node * 32 + lane];
    float ax = ef * v.x, ay = ef * v.y, az = ef * v.z, aw = ef * v.w;
    for (int j = 0; j < d; j += 8) {
        int r = d - j;          // >= 1
        int b = start + j;
        int s0 = ssrc[b];
        int s1 = ssrc[b + ((r > 1) ? 1 : 0)];
        int s2 = ssrc[b + ((r > 2) ? 2 : 0)];
        int s3 = ssrc[b + ((r > 3) ? 3 : 0)];
        int s4i = ssrc[b + ((r > 4) ? 4 : 0)];
        int s5 = ssrc[b + ((r > 5) ? 5 : 0)];
        int s6 = ssrc[b + ((r > 6) ? 6 : 0)];
        int s7 = ssrc[b + ((r > 7) ? 7 : 0)];
        float4 x0 = x4[s0 * 32 + lane];
        float4 x1 = x4[s1 * 32 + lane];
        float4 x2 = x4[s2 * 32 + lane];
        float4 x3 = x4[s3 * 32 + lane];
        float4 x4v = x4[s4i * 32 + lane];
        float4 x5 = x4[s5 * 32 + lane];
        float4 x6 = x4[s6 * 32 + lane];
        float4 x7 = x4[s7 * 32 + lane];
        float m1 = (r > 1) ? 1.f : 0.f;
        float m2 = (r > 2) ? 1.f : 0.f;
        float m3 = (r > 3) ? 1.f : 0.f;
        float m4 = (r > 4) ? 1.f : 0.f;
        float m5 = (r > 5) ? 1.f : 0.f;
        float m6 = (r > 6) ? 1.f : 0.f;
        float m7 = (r > 7) ? 1.f : 0.f;
        ax += x0.x; ay += x0.y; az += x0.z; aw += x0.w;
        ax += m1 * x1.x; ay += m1 * x1.y; az += m1 * x1.z; aw += m1 * x1.w;
        ax += m2 * x2.x; ay += m2 * x2.y; az += m2 * x2.z; aw += m2 * x2.w;
        ax += m3 * x3.x; ay += m3 * x3.y; az += m3 * x3.z; aw += m3 * x3.w;
        ax += m4 * x4v.x; ay += m4 * x4v.y; az += m4 * x4v.z; aw += m4 * x4v.w;
        ax += m5 * x5.x; ay += m5 * x5.y; az += m5 * x5.z; aw += m5 * x5.w;
        ax += m6 * x6.x; ay += m6 * x6.y; az += m6 * x6.z; aw += m6 * x6.w;
        ax += m7 * x7.x; ay += m7 * x7.y; az += m7 * x7.z; aw += m7 * x7.w;
    }
    ushort4 u;
    u.x = f2bf(ax); u.y = f2bf(ay); u.z = f2bf(az); u.w = f2bf(aw);
    hout[node * 32 + lane] = u;
}

// ---------------------------------------------------------------------------
// Persistent-W GEMM + bias + BN-stat accumulation.
// Each wave holds the ENTIRE bf16 W in registers (32 x bf16x8 = 128 VGPR)
// and grid-strides over 16-row A-tiles (prefetch 1 tile ahead).
// NEW (round-6): the epilogue stages each wave's 16x128 fp32 tile through a
// wave-private padded LDS region and stores full rows as float4 — lanes 0-31
// cover 512B contiguous, fully covering 128B lines. Round-5 counters showed
// the old scattered 64B stores cost 1.7x WRITE amplification + write-allocate
// fills in FETCH (81/88 MB vs 51.2 logical).
// FUSE_BN=1: A = fp32 yin; BN(statsIn,gmm,bta)+ReLU applied in the loader.
// ---------------------------------------------------------------------------
template <int FUSE_BN>
__global__ __launch_bounds__(256, 2) void gin_gemm_k(
    const unsigned short* __restrict__ hin,
    const float* __restrict__ yin,
    const float* __restrict__ statsIn,
    const float* __restrict__ gmm,
    const float* __restrict__ bta,
    const unsigned short* __restrict__ Wbf, const float* __restrict__ bias,
    float* __restrict__ y, float* __restrict__ statsOut) {
    __shared__ __align__(16) float s_sum[128];
    __shared__ __align__(16) float s_sq[128];
    __shared__ __align__(16) float sc[128];
    __shared__ __align__(16) float sh[128];
    __shared__ __align__(16) float yst[4][16][132];  // per-wave tile, +4 pad

    const int tid = threadIdx.x;
    const int l = tid & 63, w = tid >> 6;
    const int m = l & 15, q = l >> 4;

    if (tid < 128) {
        s_sum[tid] = 0.f;
        s_sq[tid] = 0.f;
        if (FUSE_BN) {
            const float inv = 1.0f / (float)NN;
            float mean = statsIn[tid] * inv;
            float var = statsIn[128 + tid] * inv - mean * mean;
            float s = gmm[tid] * rsqrtf(var + 1e-5f);
            sc[tid] = s;
            sh[tid] = bta[tid] - mean * s;
        }
    }

    // --- whole W into registers, once per wave ---
    bf16x8 wf[8][4];
#pragma unroll
    for (int ct = 0; ct < 8; ++ct) {
        const unsigned short* wr = Wbf + (size_t)(ct * 16 + m) * 128 + q * 8;
#pragma unroll
        for (int kc = 0; kc < 4; ++kc) {
            BF8 t;
            t.i4 = *(const int4*)(wr + kc * 32);
            wf[ct][kc] = t.v;
        }
    }
    float bc[8];
#pragma unroll
    for (int ct = 0; ct < 8; ++ct) bc[ct] = bias[ct * 16 + m];

    float ps[8], pq[8];
#pragma unroll
    for (int ct = 0; ct < 8; ++ct) { ps[ct] = 0.f; pq[ct] = 0.f; }

    __syncthreads();  // s_sum/s_sq (and sc/sh) visible

    const int NT = NN / 16;              // 6250, exact
    const int stride = gridDim.x * 4;    // waves total
    int t = blockIdx.x * 4 + w;

    const unsigned short* abase = hin + (size_t)m * 128 + q * 8;
    const float* ybase = yin + (size_t)m * 128 + q * 8;

    int4 ra[4];      // FUSE_BN=0 prefetch
    float4 rf[8];    // FUSE_BN=1 prefetch
    if (t < NT) {
        if (FUSE_BN) {
            const float* yp = ybase + (size_t)t * (16 * 128);
#pragma unroll
            for (int i = 0; i < 8; ++i)
                rf[i] = *(const float4*)(yp + (i >> 1) * 32 + (i & 1) * 4);
        } else {
            const unsigned short* ap = abase + (size_t)t * (16 * 128);
#pragma unroll
            for (int kc = 0; kc < 4; ++kc) ra[kc] = *(const int4*)(ap + kc * 32);
        }
    }

    while (t < NT) {
        // consume prefetched raw A into bf16 fragment regs
        bf16x8 a[4];
#pragma unroll
        for (int kc = 0; kc < 4; ++kc) {
            if (FUSE_BN) {
                float4 v0 = rf[2 * kc], v1 = rf[2 * kc + 1];
                float4 s0 = *(const float4*)(sc + kc * 32 + q * 8);
                float4 s1 = *(const float4*)(sc + kc * 32 + q * 8 + 4);
                float4 h0 = *(const float4*)(sh + kc * 32 + q * 8);
                float4 h1 = *(const float4*)(sh + kc * 32 + q * 8 + 4);
                BF8 tt;
                tt.u[0] = f2bf(fmaxf(v0.x * s0.x + h0.x, 0.f));
                tt.u[1] = f2bf(fmaxf(v0.y * s0.y + h0.y, 0.f));
                tt.u[2] = f2bf(fmaxf(v0.z * s0.z + h0.z, 0.f));
                tt.u[3] = f2bf(fmaxf(v0.w * s0.w + h0.w, 0.f));
                tt.u[4] = f2bf(fmaxf(v1.x * s1.x + h1.x, 0.f));
                tt.u[5] = f2bf(fmaxf(v1.y * s1.y + h1.y, 0.f));
                tt.u[6] = f2bf(fmaxf(v1.z * s1.z + h1.z, 0.f));
                tt.u[7] = f2bf(fmaxf(v1.w * s1.w + h1.w, 0.f));
                a[kc] = tt.v;
            } else {
                BF8 tt;
                tt.i4 = ra[kc];
                a[kc] = tt.v;
            }
        }

        // issue next tile's loads before compute (hidden under MFMA+stores)
        int tn = t + stride;
        if (tn < NT) {
            if (FUSE_BN) {
                const float* yp = ybase + (size_t)tn * (16 * 128);
#pragma unroll
                for (int i = 0; i < 8; ++i)
                    rf[i] = *(const float4*)(yp + (i >> 1) * 32 + (i & 1) * 4);
            } else {
                const unsigned short* ap = abase + (size_t)tn * (16 * 128);
#pragma unroll
                for (int kc = 0; kc < 4; ++kc) ra[kc] = *(const int4*)(ap + kc * 32);
            }
        }

        floatx4 acc[8];
#pragma unroll
        for (int ct = 0; ct < 8; ++ct) acc[ct] = (floatx4)0.0f;
#pragma unroll
        for (int kc = 0; kc < 4; ++kc)
#pragma unroll
            for (int ct = 0; ct < 8; ++ct)
                acc[ct] = __builtin_amdgcn_mfma_f32_16x16x32_bf16(a[kc], wf[ct][kc], acc[ct], 0, 0, 0);

        // epilogue: bias + stats, stage tile in wave-private LDS (2-way bank
        // aliasing = free), then store full float4 rows (lanes 0-31 = 512B
        // contiguous -> fully covered 128B lines, no RMW/partial-line cost).
#pragma unroll
        for (int ct = 0; ct < 8; ++ct) {
#pragma unroll
            for (int i = 0; i < 4; ++i) {
                float yv = acc[ct][i] + bc[ct];
                yst[w][q * 4 + i][ct * 16 + m] = yv;
                ps[ct] += yv;
                pq[ct] += yv * yv;
            }
        }
        asm volatile("s_waitcnt lgkmcnt(0)" ::: "memory");
        float* yb = y + (size_t)t * (16 * 128);
#pragma unroll
        for (int it = 0; it < 8; ++it) {
            int f4 = it * 64 + l;
            int row = f4 >> 5, c4 = f4 & 31;
            float4 vv = *(const float4*)&yst[w][row][c4 * 4];
            *(float4*)(yb + row * 128 + c4 * 4) = vv;
        }
        t = tn;
    }

    // flush register stats: LDS reduce, then 2 global atomics per column
#pragma unroll
    for (int ct = 0; ct < 8; ++ct) {
        atomicAdd(&s_sum[ct * 16 + m], ps[ct]);
        atomicAdd(&s_sq[ct * 16 + m], pq[ct]);
    }
    __syncthreads();
    if (tid < 128) {
        unsafeAtomicAdd(&statsOut[tid], s_sum[tid]);
        unsafeAtomicAdd(&statsOut[128 + tid], s_sq[tid]);
    }
}

// ---------------------------------------------------------------------------
// BN(train, biased var) + ReLU, fp32 in place (final layer only).
// ---------------------------------------------------------------------------
__global__ __launch_bounds__(256) void bn_relu_k(
    const float* __restrict__ y, const float* __restrict__ stats,
    const float* __restrict__ g, const float* __restrict__ beta,
    float* __restrict__ outf) {
    __shared__ __align__(16) float sc[128];
    __shared__ __align__(16) float sh[128];
    int t = threadIdx.x;
    if (t < 128) {
        const float inv = 1.0f / (float)NN;
        float mean = stats[t] * inv;
        float var = stats[128 + t] * inv - mean * mean;
        float s = g[t] * rsqrtf(var + 1e-5f);
        sc[t] = s;
        sh[t] = beta[t] - mean * s;
    }
    __syncthreads();
    const int total4 = NN * 32;
    const float4* y4 = (const float4*)y;
    for (int i = blockIdx.x * 256 + t; i < total4; i += gridDim.x * 256) {
        int c4 = i & 31;
        float4 v = y4[i];
        float4 s = ((const float4*)sc)[c4];
        float4 b = ((const float4*)sh)[c4];
        float r0 = fmaxf(v.x * s.x + b.x, 0.f);
        float r1 = fmaxf(v.y * s.y + b.y, 0.f);
        float r2 = fmaxf(v.z * s.z + b.z, 0.f);
        float r3 = fmaxf(v.w * s.w + b.w, 0.f);
        ((float4*)outf)[i] = make_float4(r0, r1, r2, r3);
    }
}

// ---------------------------------------------------------------------------
extern "C" void kernel_launch(void* const* d_in, const int* in_sizes, int n_in,
                              void* d_out, int out_size, void* d_ws, size_t ws_size,
                              hipStream_t stream) {
    const float* x   = (const float*)d_in[0];
    const int* ei    = (const int*)d_in[1];   // int64 in ref -> int32 from harness
    const float* eps = (const float*)d_in[2];
    const float* W1  = (const float*)d_in[3];
    const float* b1  = (const float*)d_in[4];
    const float* g1  = (const float*)d_in[5];
    const float* be1 = (const float*)d_in[6];
    const float* W2  = (const float*)d_in[7];
    const float* b2  = (const float*)d_in[8];
    const float* g2  = (const float*)d_in[9];
    const float* be2 = (const float*)d_in[10];
    float* out = (float*)d_out;

    // Workspace (~29.6 MB): [csr][hbuf bf16 25.6MB][stats 2KB][wbf 64KB]
    // gemm1 hbuf->out (y1); gemm2 reads y1 with fused BN1+ReLU, in-place ->
    // out (y2); bn_relu finishes BN2 in place.
    int* deg        = (int*)d_ws;           // NPAD
    int* offs       = deg + NPAD;           // NPAD
    int* cursor     = offs + NPAD;          // NPAD
    int* chunkSums  = cursor + NPAD;        // 512
    int* ssrc       = chunkSums + 512;      // EE + pad
    unsigned short* hbuf = (unsigned short*)(ssrc + EE + 256);   // N*D bf16
    float* stats    = (float*)(hbuf + (size_t)NN * DD);          // 512
    unsigned short* wbf = (unsigned short*)(stats + 512);        // 2*128*128 bf16

    hipMemsetAsync(deg, 0, NPAD * sizeof(int), stream);
    hipMemsetAsync(stats, 0, 512 * sizeof(float), stream);

    const int numChunks = (NN + 255) / 256;  // 391
    hist_k<<<(EE + 255) / 256, 256, 0, stream>>>(ei, deg);
    scan1_k<<<numChunks, 256, 0, stream>>>(deg, offs, chunkSums);
    scan2_k<<<1, 512, 0, stream>>>(chunkSums, numChunks);
    scan3_k<<<numChunks, 256, 0, stream>>>(offs, chunkSums, cursor);
    esort_k<<<(EE + 255) / 256, 256, 0, stream>>>(ei, cursor, ssrc);
    aggregate_k<<<(NN * 32 + 255) / 256, 256, 0, stream>>>(
        (const float4*)x, ssrc, offs, deg, eps, (ushort4*)hbuf);
    wconv_k<<<32, 256, 0, stream>>>(W1, W2, wbf);

    const int gblocks = 512;  // ~2 blocks/CU, persistent grid-stride
    gin_gemm_k<0><<<gblocks, 256, 0, stream>>>(
        hbuf, nullptr, nullptr, nullptr, nullptr, wbf, b1, out, stats);
    gin_gemm_k<1><<<gblocks, 256, 0, stream>>>(
        nullptr, out, stats, g1, be1, wbf + 16384, b2, out, stats + 256);
    bn_relu_k<<<4096, 256, 0, stream>>>(out, stats + 256, g2, be2, out);
}